// Round 2
// baseline (318.207 us; speedup 1.0000x reference)
//
#include <hip/hip_runtime.h>
#include <hip/hip_bf16.h>

// EdgeDecoder: out[e] = W2 @ relu(W1 @ [z[src]; z[dst]] + b1) + b2
// Restructure: W1 = [W1a | W1b] over the concat ->
//   U[n] = W1a @ z[n], V[n] = W1b @ z[n]  (3.28 GFLOP once, not 42 GFLOP/edges)
//   out[e] = dot(relu(U[src]+V[dst]+b1), W2) + b2
// Dtypes per reference: fp32 inputs/output, int32 edge_index.
// U/V stored bf16 in d_ws (25.6 MB, L2/L3-resident) to halve phase-2 gathers.

#define N_NODES 50000
#define N_EDGES 640000
#define H 128
#define NPW 8  // nodes per wave, phase 1: cuts per-wave W1 L2 traffic 8x

using bf16 = __hip_bfloat16;
using bf162 = __hip_bfloat162;

__device__ __forceinline__ float2 cvt2(bf162 h) { return __bfloat1622float2(h); }

// Phase 1: each wave handles NPW nodes. Lane split: l16 = lane&15 owns the
// 8-float K-chunk [l16*8, l16*8+8) (two float4 loads, 512 B contiguous per
// 16-lane group); g = lane>>4 picks 1 of 4 outputs per iteration. 4-step
// shfl_xor reduce within each 16-lane group, amortized over NPW dots.
__global__ __launch_bounds__(256) void precompute_uv(
    const float* __restrict__ z, const float* __restrict__ W1,
    bf16* __restrict__ U, bf16* __restrict__ V) {
  const int lane = threadIdx.x & 63;
  const int wave = blockIdx.x * 4 + (threadIdx.x >> 6);
  const int nb = wave * NPW;
  if (nb >= N_NODES) return;
  const int l16 = lane & 15;
  const int g = lane >> 4;

  float zr[NPW][8];
#pragma unroll
  for (int m = 0; m < NPW; ++m) {
    int node = nb + m;
    if (node >= N_NODES) node = N_NODES - 1;  // clamp: dup load, store guarded
    const float4* zp = reinterpret_cast<const float4*>(z + (size_t)node * H) + l16 * 2;
    const float4 a = zp[0], b = zp[1];
    zr[m][0] = a.x; zr[m][1] = a.y; zr[m][2] = a.z; zr[m][3] = a.w;
    zr[m][4] = b.x; zr[m][5] = b.y; zr[m][6] = b.z; zr[m][7] = b.w;
  }

  for (int ob = 0; ob < 2 * H; ob += 4) {
    const int o = ob + g;          // output index in [0,256)
    const int half = o >> 7;       // 0 -> U, 1 -> V
    const int j = o & (H - 1);     // hidden index
    const float4* wp =
        reinterpret_cast<const float4*>(W1 + (size_t)j * (2 * H) + half * H) + l16 * 2;
    const float4 wa = wp[0], wb = wp[1];
    const float w[8] = {wa.x, wa.y, wa.z, wa.w, wb.x, wb.y, wb.z, wb.w};
    float s[NPW];
#pragma unroll
    for (int m = 0; m < NPW; ++m) {
      float acc = 0.f;
#pragma unroll
      for (int k = 0; k < 8; ++k) acc += zr[m][k] * w[k];
      s[m] = acc;
    }
#pragma unroll
    for (int st = 1; st < 16; st <<= 1) {
#pragma unroll
      for (int m = 0; m < NPW; ++m) s[m] += __shfl_xor(s[m], st);
    }
    if (l16 == 0) {
      bf16* dst = half ? V : U;
#pragma unroll
      for (int m = 0; m < NPW; ++m)
        if (nb + m < N_NODES)
          dst[(size_t)(nb + m) * H + j] = __float2bfloat16(s[m]);
    }
  }
}

// Phase 2: one wave per 64-edge chunk so idx loads and output stores are
// coalesced. Lane owns hidden pair {2*lane, 2*lane+1}; per edge i the wave
// gathers U[src_i], V[dst_i] (256 B each, bf16), relu+dot, butterfly-reduce.
__global__ __launch_bounds__(256) void edge_decode(
    const int* __restrict__ eidx,
    const bf16* __restrict__ U, const bf16* __restrict__ V,
    const float* __restrict__ bias1, const float* __restrict__ W2,
    const float* __restrict__ bias2, float* __restrict__ out) {
  const int lane = threadIdx.x & 63;
  const int wave = (int)((blockIdx.x * blockDim.x + threadIdx.x) >> 6);
  const int nwaves = (int)((gridDim.x * blockDim.x) >> 6);

  const float2 b1 = reinterpret_cast<const float2*>(bias1)[lane];
  const float2 w2 = reinterpret_cast<const float2*>(W2)[lane];
  const float b2 = bias2[0];
  const bf162* U2 = reinterpret_cast<const bf162*>(U);
  const bf162* V2 = reinterpret_cast<const bf162*>(V);

  for (int chunk = wave * 64; chunk < N_EDGES; chunk += nwaves * 64) {
    const int src = eidx[chunk + lane];
    const int dst = eidx[N_EDGES + chunk + lane];
    float res = 0.f;
#pragma unroll 8
    for (int i = 0; i < 64; ++i) {
      const int s_i = __shfl(src, i);
      const int d_i = __shfl(dst, i);
      const float2 u = cvt2(U2[(size_t)s_i * (H / 2) + lane]);
      const float2 v = cvt2(V2[(size_t)d_i * (H / 2) + lane]);
      float h0 = u.x + v.x + b1.x; h0 = h0 > 0.f ? h0 : 0.f;
      float h1 = u.y + v.y + b1.y; h1 = h1 > 0.f ? h1 : 0.f;
      float s = h0 * w2.x + h1 * w2.y;
      s += __shfl_xor(s, 32);
      s += __shfl_xor(s, 16);
      s += __shfl_xor(s, 8);
      s += __shfl_xor(s, 4);
      s += __shfl_xor(s, 2);
      s += __shfl_xor(s, 1);
      if (lane == i) res = s + b2;  // lane i keeps edge i's result
    }
    out[chunk + lane] = res;  // coalesced 4 B/lane store
  }
}

extern "C" void kernel_launch(void* const* d_in, const int* in_sizes, int n_in,
                              void* d_out, int out_size, void* d_ws, size_t ws_size,
                              hipStream_t stream) {
  const float* z     = (const float*)d_in[0];
  const float* W1    = (const float*)d_in[1];
  const float* bias1 = (const float*)d_in[2];
  const float* W2    = (const float*)d_in[3];
  const float* bias2 = (const float*)d_in[4];
  const int*   eidx  = (const int*)d_in[5];
  float* out = (float*)d_out;

  bf16* U = (bf16*)d_ws;              // [N_NODES, H] bf16
  bf16* V = U + (size_t)N_NODES * H;  // [N_NODES, H] bf16 (25.6 MB total)

  // Phase 1: 6250 waves (8 nodes each) -> 1563 blocks of 4 waves.
  const int waves1 = (N_NODES + NPW - 1) / NPW;
  const int blocks1 = (waves1 + 3) / 4;
  hipLaunchKernelGGL(precompute_uv, dim3(blocks1), dim3(256), 0, stream, z, W1, U, V);

  // Phase 2: 625 blocks * 4 waves = 2500 waves; 10000 chunks -> 4 chunks/wave.
  hipLaunchKernelGGL(edge_decode, dim3(625), dim3(256), 0, stream,
                     eidx, U, V, bias1, W2, bias2, out);
}

// Round 3
// 151.626 us; speedup vs baseline: 2.0986x; 2.0986x over previous
//
#include <hip/hip_runtime.h>
#include <hip/hip_bf16.h>

// EdgeDecoder: out[e] = W2 @ relu(W1 @ [z[src]; z[dst]] + b1) + b2
// Restructure: W1 = [W1a | W1b] over the concat ->
//   U[n] = W1a @ z[n], V[n] = W1b @ z[n]  (3.28 GFLOP once, via MFMA)
//   out[e] = dot(relu(U[src]+V[dst]+b1), W2) + b2
// Phase 1 computes C'[o, node] = W1t^T . z^T with mfma_f32_16x16x32_bf16 so
// the C/D layout (col=lane&15 -> node, row=quad*4+reg -> output) gives each
// lane 4 consecutive outputs of one node: one packed 8B store, no transpose.
// U/V stored bf16 in d_ws (25.6 MB, L2/L3-resident) to halve phase-2 gathers.

#define N_NODES 50000
#define N_EDGES 640000
#define H 128

using bf16 = __hip_bfloat16;
typedef __attribute__((ext_vector_type(8))) short short8;  // 8 bf16, 4 VGPRs
typedef __attribute__((ext_vector_type(4))) float f32x4;   // MFMA acc

static __device__ __forceinline__ short bfbits(float x) {
  __hip_bfloat16 h = __float2bfloat16(x);
  return *reinterpret_cast<short*>(&h);
}

static __device__ __forceinline__ short8 pack8(float4 a, float4 b) {
  short8 r;
  r[0] = bfbits(a.x); r[1] = bfbits(a.y); r[2] = bfbits(a.z); r[3] = bfbits(a.w);
  r[4] = bfbits(b.x); r[5] = bfbits(b.y); r[6] = bfbits(b.z); r[7] = bfbits(b.w);
  return r;
}

// Phase 1: block = 4 waves; wave s owns outputs [s*64, s*64+64), block owns a
// 64-node tile. A-frag (W1t^T): lane holds o=base+(l&15), k=quad*8..+8 -> 8
// consecutive fp32 of a W1 row. B-frag (z^T): lane holds node=base+(l&15),
// k=quad*8..+8 -> 8 consecutive fp32 of a z row. K=128 = 4 MFMA steps.
__global__ __launch_bounds__(256) void precompute_uv(
    const float* __restrict__ z, const float* __restrict__ W1,
    bf16* __restrict__ U, bf16* __restrict__ V) {
  const int lane = threadIdx.x & 63;
  const int s = threadIdx.x >> 6;  // o-split 0..3
  const int l15 = lane & 15, quad = lane >> 4;
  const int nodebase = blockIdx.x * 64;

  short8 wf[4][4];  // [o-tile][k-step], register-resident (W1 ~L2-hit)
#pragma unroll
  for (int t = 0; t < 4; ++t) {
    const int o = s * 64 + t * 16 + l15;
    const float* wp = W1 + (size_t)(o & (H - 1)) * (2 * H) + (o >> 7) * H + quad * 8;
#pragma unroll
    for (int q = 0; q < 4; ++q) {
      const float4* p = reinterpret_cast<const float4*>(wp + q * 32);
      wf[t][q] = pack8(p[0], p[1]);
    }
  }

  for (int msub = 0; msub < 4; ++msub) {
    const int node = nodebase + msub * 16 + l15;
    const int nodeC = node < N_NODES ? node : N_NODES - 1;  // clamp loads
    short8 zf[4];
    const float* zp = z + (size_t)nodeC * H + quad * 8;
#pragma unroll
    for (int q = 0; q < 4; ++q) {
      const float4* p = reinterpret_cast<const float4*>(zp + q * 32);
      zf[q] = pack8(p[0], p[1]);
    }
    f32x4 acc[4] = {};
#pragma unroll
    for (int t = 0; t < 4; ++t)
#pragma unroll
      for (int q = 0; q < 4; ++q)
        acc[t] = __builtin_amdgcn_mfma_f32_16x16x32_bf16(wf[t][q], zf[q], acc[t], 0, 0, 0);

    if (node < N_NODES) {
#pragma unroll
      for (int t = 0; t < 4; ++t) {
        const int o = s * 64 + t * 16 + quad * 4;  // 4 consecutive outputs
        bf16* base = (o < H) ? U : V;
        ushort4 st;
        st.x = (unsigned short)bfbits(acc[t][0]);
        st.y = (unsigned short)bfbits(acc[t][1]);
        st.z = (unsigned short)bfbits(acc[t][2]);
        st.w = (unsigned short)bfbits(acc[t][3]);
        *reinterpret_cast<ushort4*>(base + (size_t)node * H + (o & (H - 1))) = st;
      }
    }
  }
}

static __device__ __forceinline__ void acc2(unsigned u, unsigned v,
                                            float b1lo, float b1hi,
                                            float w2lo, float w2hi, float& sum) {
  const float ulo = __uint_as_float(u << 16);
  const float uhi = __uint_as_float(u & 0xffff0000u);
  const float vlo = __uint_as_float(v << 16);
  const float vhi = __uint_as_float(v & 0xffff0000u);
  float h0 = ulo + vlo + b1lo; h0 = fmaxf(h0, 0.f);
  float h1 = uhi + vhi + b1hi; h1 = fmaxf(h1, 0.f);
  sum = fmaf(h0, w2lo, sum);
  sum = fmaf(h1, w2hi, sum);
}

// Phase 2: one wave per 64-edge chunk. 8-lane group per edge; lane owns 16
// hidden elems ((lane&7)*16..+16) = 2x16B U loads + 2x16B V loads, then a
// 3-step butterfly within the group. Iteration i: group g handles edge
// chunk + g*8 + i; lane l keeps i == (l&7) so lane l ends with edge chunk+l.
__global__ __launch_bounds__(256) void edge_decode(
    const int* __restrict__ eidx, const bf16* __restrict__ Ub,
    const bf16* __restrict__ Vb, const float* __restrict__ bias1,
    const float* __restrict__ W2, const float* __restrict__ bias2,
    float* __restrict__ out) {
  const int lane = threadIdx.x & 63;
  const int w = blockIdx.x * 4 + (int)(threadIdx.x >> 6);
  const int chunk = w * 64;
  const int e8 = lane & 7;

  float b1r[16], w2r[16];
  const float4* bp = reinterpret_cast<const float4*>(bias1 + e8 * 16);
  const float4* wp = reinterpret_cast<const float4*>(W2 + e8 * 16);
#pragma unroll
  for (int q = 0; q < 4; ++q) {
    const float4 b = bp[q], wv = wp[q];
    b1r[q * 4 + 0] = b.x; b1r[q * 4 + 1] = b.y; b1r[q * 4 + 2] = b.z; b1r[q * 4 + 3] = b.w;
    w2r[q * 4 + 0] = wv.x; w2r[q * 4 + 1] = wv.y; w2r[q * 4 + 2] = wv.z; w2r[q * 4 + 3] = wv.w;
  }
  const float b2 = bias2[0];

  const int src = eidx[chunk + lane];
  const int dst = eidx[N_EDGES + chunk + lane];
  const uint4* U4 = reinterpret_cast<const uint4*>(Ub);  // row = 16 uint4
  const uint4* V4 = reinterpret_cast<const uint4*>(Vb);

  float res = 0.f;
#pragma unroll
  for (int i = 0; i < 8; ++i) {
    const int sl = (lane & 56) + i;
    const int s_i = __shfl(src, sl);
    const int d_i = __shfl(dst, sl);
    const uint4* up = U4 + (size_t)s_i * 16 + e8 * 2;
    const uint4* vp = V4 + (size_t)d_i * 16 + e8 * 2;
    const uint4 ua = up[0], ub = up[1], va = vp[0], vb = vp[1];
    float sum = 0.f;
    acc2(ua.x, va.x, b1r[0],  b1r[1],  w2r[0],  w2r[1],  sum);
    acc2(ua.y, va.y, b1r[2],  b1r[3],  w2r[2],  w2r[3],  sum);
    acc2(ua.z, va.z, b1r[4],  b1r[5],  w2r[4],  w2r[5],  sum);
    acc2(ua.w, va.w, b1r[6],  b1r[7],  w2r[6],  w2r[7],  sum);
    acc2(ub.x, vb.x, b1r[8],  b1r[9],  w2r[8],  w2r[9],  sum);
    acc2(ub.y, vb.y, b1r[10], b1r[11], w2r[10], w2r[11], sum);
    acc2(ub.z, vb.z, b1r[12], b1r[13], w2r[12], w2r[13], sum);
    acc2(ub.w, vb.w, b1r[14], b1r[15], w2r[14], w2r[15], sum);
    sum += __shfl_xor(sum, 1);
    sum += __shfl_xor(sum, 2);
    sum += __shfl_xor(sum, 4);
    if (e8 == i) res = sum + b2;
  }
  out[chunk + lane] = res;  // coalesced 4 B/lane
}

extern "C" void kernel_launch(void* const* d_in, const int* in_sizes, int n_in,
                              void* d_out, int out_size, void* d_ws, size_t ws_size,
                              hipStream_t stream) {
  const float* z     = (const float*)d_in[0];
  const float* W1    = (const float*)d_in[1];
  const float* bias1 = (const float*)d_in[2];
  const float* W2    = (const float*)d_in[3];
  const float* bias2 = (const float*)d_in[4];
  const int*   eidx  = (const int*)d_in[5];
  float* out = (float*)d_out;

  bf16* U = (bf16*)d_ws;              // [N_NODES, H] bf16
  bf16* V = U + (size_t)N_NODES * H;  // [N_NODES, H] bf16 (25.6 MB total)

  // Phase 1: 782 blocks x 4 waves; each block = 64-node tile, wave = 64-output split.
  hipLaunchKernelGGL(precompute_uv, dim3((N_NODES + 63) / 64), dim3(256), 0, stream,
                     z, W1, U, V);
  // Phase 2: 10000 waves, one 64-edge chunk each.
  hipLaunchKernelGGL(edge_decode, dim3(N_EDGES / 64 / 4), dim3(256), 0, stream,
                     eidx, U, V, bias1, W2, bias2, out);
}

// Round 4
// 148.265 us; speedup vs baseline: 2.1462x; 1.0227x over previous
//
#include <hip/hip_runtime.h>
#include <hip/hip_bf16.h>

// EdgeDecoder: out[e] = W2 @ relu(W1 @ [z[src]; z[dst]] + b1) + b2
// Restructure: W1 = [W1a | W1b] over the concat ->
//   U[n] = W1a @ z[n], V[n] = W1b @ z[n]  (3.28 GFLOP once, via MFMA)
//   out[e] = dot(relu(U[src]+V[dst]+b1), W2) + b2
// Phase 1 computes C'[o, node] = W1t^T . z^T with mfma_f32_16x16x32_bf16 so
// the C/D layout (col=lane&15 -> node, row=quad*4+reg -> output) gives each
// lane 4 consecutive outputs of one node: one packed 8B store, no transpose.
// U/V stored bf16 in d_ws (25.6 MB) to halve phase-2 gathers.
// Phase 2 R4: gathers batched 4 edges deep (16 outstanding uint4 loads/lane)
// to hide L2/L3 latency — R3 counters showed latency-bound (VALU 28%, HBM 44%,
// effective gather 7.2 TB/s < L3 ceiling).

#define N_NODES 50000
#define N_EDGES 640000
#define H 128

using bf16 = __hip_bfloat16;
typedef __attribute__((ext_vector_type(8))) short short8;  // 8 bf16, 4 VGPRs
typedef __attribute__((ext_vector_type(4))) float f32x4;   // MFMA acc

static __device__ __forceinline__ short bfbits(float x) {
  __hip_bfloat16 h = __float2bfloat16(x);
  return *reinterpret_cast<short*>(&h);
}

static __device__ __forceinline__ short8 pack8(float4 a, float4 b) {
  short8 r;
  r[0] = bfbits(a.x); r[1] = bfbits(a.y); r[2] = bfbits(a.z); r[3] = bfbits(a.w);
  r[4] = bfbits(b.x); r[5] = bfbits(b.y); r[6] = bfbits(b.z); r[7] = bfbits(b.w);
  return r;
}

// Phase 1: block = 4 waves; wave s owns outputs [s*64, s*64+64), block owns a
// 64-node tile. K=128 = 4 MFMA steps; W-frags register-resident (W1 L2-hit).
__global__ __launch_bounds__(256) void precompute_uv(
    const float* __restrict__ z, const float* __restrict__ W1,
    bf16* __restrict__ U, bf16* __restrict__ V) {
  const int lane = threadIdx.x & 63;
  const int s = threadIdx.x >> 6;  // o-split 0..3
  const int l15 = lane & 15, quad = lane >> 4;
  const int nodebase = blockIdx.x * 64;

  short8 wf[4][4];  // [o-tile][k-step]
#pragma unroll
  for (int t = 0; t < 4; ++t) {
    const int o = s * 64 + t * 16 + l15;
    const float* wp = W1 + (size_t)(o & (H - 1)) * (2 * H) + (o >> 7) * H + quad * 8;
#pragma unroll
    for (int q = 0; q < 4; ++q) {
      const float4* p = reinterpret_cast<const float4*>(wp + q * 32);
      wf[t][q] = pack8(p[0], p[1]);
    }
  }

  for (int msub = 0; msub < 4; ++msub) {
    const int node = nodebase + msub * 16 + l15;
    const int nodeC = node < N_NODES ? node : N_NODES - 1;  // clamp loads
    short8 zf[4];
    const float* zp = z + (size_t)nodeC * H + quad * 8;
#pragma unroll
    for (int q = 0; q < 4; ++q) {
      const float4* p = reinterpret_cast<const float4*>(zp + q * 32);
      zf[q] = pack8(p[0], p[1]);
    }
    f32x4 acc[4] = {};
#pragma unroll
    for (int t = 0; t < 4; ++t)
#pragma unroll
      for (int q = 0; q < 4; ++q)
        acc[t] = __builtin_amdgcn_mfma_f32_16x16x32_bf16(wf[t][q], zf[q], acc[t], 0, 0, 0);

    if (node < N_NODES) {
#pragma unroll
      for (int t = 0; t < 4; ++t) {
        const int o = s * 64 + t * 16 + quad * 4;  // 4 consecutive outputs
        bf16* base = (o < H) ? U : V;
        ushort4 st;
        st.x = (unsigned short)bfbits(acc[t][0]);
        st.y = (unsigned short)bfbits(acc[t][1]);
        st.z = (unsigned short)bfbits(acc[t][2]);
        st.w = (unsigned short)bfbits(acc[t][3]);
        *reinterpret_cast<ushort4*>(base + (size_t)node * H + (o & (H - 1))) = st;
      }
    }
  }
}

static __device__ __forceinline__ void acc2(unsigned u, unsigned v,
                                            float b1lo, float b1hi,
                                            float w2lo, float w2hi, float& sum) {
  const float ulo = __uint_as_float(u << 16);
  const float uhi = __uint_as_float(u & 0xffff0000u);
  const float vlo = __uint_as_float(v << 16);
  const float vhi = __uint_as_float(v & 0xffff0000u);
  float h0 = ulo + vlo + b1lo; h0 = fmaxf(h0, 0.f);
  float h1 = uhi + vhi + b1hi; h1 = fmaxf(h1, 0.f);
  sum = fmaf(h0, w2lo, sum);
  sum = fmaf(h1, w2hi, sum);
}

// Phase 2: one wave per 64-edge chunk. 8-lane group per edge; lane owns 16
// hidden elems = 2x16B U loads + 2x16B V loads. Gathers batched 4 edges deep:
// all 16 uint4 loads issued before any compute (MLP to hide ~200-900cy lat).
// Iteration i: group g handles edge chunk + g*8 + i; lane keeps i == (l&7).
__global__ __launch_bounds__(256, 4) void edge_decode(
    const int* __restrict__ eidx, const bf16* __restrict__ Ub,
    const bf16* __restrict__ Vb, const float* __restrict__ bias1,
    const float* __restrict__ W2, const float* __restrict__ bias2,
    float* __restrict__ out) {
  const int lane = threadIdx.x & 63;
  const int w = blockIdx.x * 4 + (int)(threadIdx.x >> 6);
  const int chunk = w * 64;
  const int e8 = lane & 7;

  float b1r[16], w2r[16];
  const float4* bp = reinterpret_cast<const float4*>(bias1 + e8 * 16);
  const float4* wp = reinterpret_cast<const float4*>(W2 + e8 * 16);
#pragma unroll
  for (int q = 0; q < 4; ++q) {
    const float4 b = bp[q], wv = wp[q];
    b1r[q * 4 + 0] = b.x; b1r[q * 4 + 1] = b.y; b1r[q * 4 + 2] = b.z; b1r[q * 4 + 3] = b.w;
    w2r[q * 4 + 0] = wv.x; w2r[q * 4 + 1] = wv.y; w2r[q * 4 + 2] = wv.z; w2r[q * 4 + 3] = wv.w;
  }
  const float b2 = bias2[0];

  const int src = eidx[chunk + lane];
  const int dst = eidx[N_EDGES + chunk + lane];
  const uint4* U4 = reinterpret_cast<const uint4*>(Ub);  // row = 16 uint4
  const uint4* V4 = reinterpret_cast<const uint4*>(Vb);

  float res = 0.f;
#pragma unroll
  for (int half = 0; half < 2; ++half) {
    uint4 ua[4], ub[4], va[4], vb[4];
    // Batch: issue all 16 gather loads for 4 edges before any compute.
#pragma unroll
    for (int j = 0; j < 4; ++j) {
      const int i = half * 4 + j;
      const int sl = (lane & 56) + i;
      const int s_i = __shfl(src, sl);
      const int d_i = __shfl(dst, sl);
      const uint4* up = U4 + (size_t)s_i * 16 + e8 * 2;
      const uint4* vp = V4 + (size_t)d_i * 16 + e8 * 2;
      ua[j] = up[0]; ub[j] = up[1];
      va[j] = vp[0]; vb[j] = vp[1];
    }
#pragma unroll
    for (int j = 0; j < 4; ++j) {
      const int i = half * 4 + j;
      float sum = 0.f;
      acc2(ua[j].x, va[j].x, b1r[0],  b1r[1],  w2r[0],  w2r[1],  sum);
      acc2(ua[j].y, va[j].y, b1r[2],  b1r[3],  w2r[2],  w2r[3],  sum);
      acc2(ua[j].z, va[j].z, b1r[4],  b1r[5],  w2r[4],  w2r[5],  sum);
      acc2(ua[j].w, va[j].w, b1r[6],  b1r[7],  w2r[6],  w2r[7],  sum);
      acc2(ub[j].x, vb[j].x, b1r[8],  b1r[9],  w2r[8],  w2r[9],  sum);
      acc2(ub[j].y, vb[j].y, b1r[10], b1r[11], w2r[10], w2r[11], sum);
      acc2(ub[j].z, vb[j].z, b1r[12], b1r[13], w2r[12], w2r[13], sum);
      acc2(ub[j].w, vb[j].w, b1r[14], b1r[15], w2r[14], w2r[15], sum);
      sum += __shfl_xor(sum, 1);
      sum += __shfl_xor(sum, 2);
      sum += __shfl_xor(sum, 4);
      if (e8 == i) res = sum + b2;
    }
  }
  out[chunk + lane] = res;  // coalesced 4 B/lane
}

extern "C" void kernel_launch(void* const* d_in, const int* in_sizes, int n_in,
                              void* d_out, int out_size, void* d_ws, size_t ws_size,
                              hipStream_t stream) {
  const float* z     = (const float*)d_in[0];
  const float* W1    = (const float*)d_in[1];
  const float* bias1 = (const float*)d_in[2];
  const float* W2    = (const float*)d_in[3];
  const float* bias2 = (const float*)d_in[4];
  const int*   eidx  = (const int*)d_in[5];
  float* out = (float*)d_out;

  bf16* U = (bf16*)d_ws;              // [N_NODES, H] bf16
  bf16* V = U + (size_t)N_NODES * H;  // [N_NODES, H] bf16 (25.6 MB total)

  // Phase 1: 782 blocks x 4 waves; block = 64-node tile, wave = 64-output split.
  hipLaunchKernelGGL(precompute_uv, dim3((N_NODES + 63) / 64), dim3(256), 0, stream,
                     z, W1, U, V);
  // Phase 2: 10000 waves, one 64-edge chunk each.
  hipLaunchKernelGGL(edge_decode, dim3(N_EDGES / 64 / 4), dim3(256), 0, stream,
                     eidx, U, V, bias1, W2, bias2, out);
}